// Round 2
// baseline (808.503 us; speedup 1.0000x reference)
//
#include <hip/hip_runtime.h>
#include <hip/hip_bf16.h>

typedef _Float16 half_t;
typedef _Float16 half8 __attribute__((ext_vector_type(8)));
typedef _Float16 half4v __attribute__((ext_vector_type(4)));
typedef float floatx4 __attribute__((ext_vector_type(4)));

// ---------------- weight transpose + fp32->fp16: Wt[n][k] = W[k][n], W is [K][N] ----------------
__global__ __launch_bounds__(256) void wtrans_kernel(const float* __restrict__ W,
                                                     half_t* __restrict__ Wt, int K, int N) {
  __shared__ float sm[32][33];
  int n0 = blockIdx.x * 32, k0 = blockIdx.y * 32;
  int x = threadIdx.x & 31, y0 = threadIdx.x >> 5;
#pragma unroll
  for (int yy = 0; yy < 4; ++yy) {
    int y = y0 + yy * 8;
    sm[y][x] = W[(size_t)(k0 + y) * N + n0 + x];
  }
  __syncthreads();
#pragma unroll
  for (int yy = 0; yy < 4; ++yy) {
    int y = y0 + yy * 8;
    Wt[(size_t)(n0 + y) * K + k0 + x] = (half_t)sm[x][y];
  }
}

// ---------------- NT GEMM: C[m][n] = sum_k A[m][k]*Bt[n][k] (+bias[n]), fp16 MFMA, fp32 acc ----------------
// tile 128x128, BK=32, 256 threads = 4 waves in 2x2, each wave 64x64 via 4x4 of 16x16x32 MFMA.
// MFMA operands SWAPPED (mfma(bf, af)): lane then owns 4 consecutive n of one row m.
template <bool AF32, bool BIAS>
__global__ __launch_bounds__(256) void gemm_nt(
    const float* __restrict__ Af, const half_t* __restrict__ Ah,
    const half_t* __restrict__ Bt, const float* __restrict__ bias,
    half_t* __restrict__ C, int K, int ldc,
    size_t aStrideZ, size_t bStrideZ, size_t cStrideZ) {
  __shared__ half_t sA[128 * 32];
  __shared__ half_t sB[128 * 32];
  const int t = threadIdx.x;
  const int m0 = blockIdx.x * 128;
  const int n0 = blockIdx.y * 128;
  const int z = blockIdx.z;
  const half_t* Bz = Bt + bStrideZ * (size_t)z;
  const int w = t >> 6, lane = t & 63;
  const int wm = w & 1, wn = w >> 1;
  const int lr = lane & 15, lk = lane >> 4;
  const int srow = t >> 2, sg = t & 3;

  floatx4 acc[4][4] = {};

  for (int k0 = 0; k0 < K; k0 += 32) {
    __syncthreads();
#pragma unroll
    for (int rep = 0; rep < 2; ++rep) {
      int row = srow + rep * 64;
      int goff = (sg ^ ((row >> 1) & 3)) * 8;
      half8 hv;
      if constexpr (AF32) {
        const float* p = Af + (size_t)(m0 + row) * K + k0 + sg * 8;
        float4 f0 = *(const float4*)p;
        float4 f1 = *(const float4*)(p + 4);
        hv[0] = (half_t)f0.x; hv[1] = (half_t)f0.y;
        hv[2] = (half_t)f0.z; hv[3] = (half_t)f0.w;
        hv[4] = (half_t)f1.x; hv[5] = (half_t)f1.y;
        hv[6] = (half_t)f1.z; hv[7] = (half_t)f1.w;
      } else {
        const half_t* p = Ah + aStrideZ * (size_t)z + (size_t)(m0 + row) * K + k0 + sg * 8;
        hv = *(const half8*)p;
      }
      *(half8*)&sA[row * 32 + goff] = hv;
      const half_t* q = Bz + (size_t)(n0 + row) * K + k0 + sg * 8;
      *(half8*)&sB[row * 32 + goff] = *(const half8*)q;
    }
    __syncthreads();
    half8 af[4], bf[4];
#pragma unroll
    for (int mt = 0; mt < 4; ++mt) {
      int row = wm * 64 + mt * 16 + lr;
      af[mt] = *(const half8*)&sA[row * 32 + ((lk ^ ((row >> 1) & 3)) * 8)];
    }
#pragma unroll
    for (int nt = 0; nt < 4; ++nt) {
      int row = wn * 64 + nt * 16 + lr;
      bf[nt] = *(const half8*)&sB[row * 32 + ((lk ^ ((row >> 1) & 3)) * 8)];
    }
#pragma unroll
    for (int mt = 0; mt < 4; ++mt)
#pragma unroll
      for (int nt = 0; nt < 4; ++nt)
        acc[mt][nt] = __builtin_amdgcn_mfma_f32_16x16x32_f16(bf[nt], af[mt], acc[mt][nt], 0, 0, 0);
  }

  half_t* Cz = C + cStrideZ * (size_t)z;
#pragma unroll
  for (int mt = 0; mt < 4; ++mt) {
    int m = m0 + wm * 64 + mt * 16 + lr;
#pragma unroll
    for (int nt = 0; nt < 4; ++nt) {
      int nb = n0 + wn * 64 + nt * 16 + lk * 4;
      floatx4 a = acc[mt][nt];
      half4v h;
      if constexpr (BIAS) {
        float4 bv = *(const float4*)&bias[nb];
        h[0] = (half_t)(a[0] + bv.x); h[1] = (half_t)(a[1] + bv.y);
        h[2] = (half_t)(a[2] + bv.z); h[3] = (half_t)(a[3] + bv.w);
      } else {
        h[0] = (half_t)a[0]; h[1] = (half_t)a[1];
        h[2] = (half_t)a[2]; h[3] = (half_t)a[3];
      }
      *(half4v*)&Cz[(size_t)m * ldc + nb] = h;
    }
  }
}

// ---------------- FUSED scores GEMM + softmax + column sums ----------------
// grid (32 qblocks, 64 z), 256 thr = 4 waves. Block computes S = Tq[z][q0:q0+32][:] @ Tk[z]^T
// (32 x 1024, K=256) entirely in fp32 MFMA accumulators (wave w owns cols [w*256,(w+1)*256):
// acc[2][16] floatx4 = 128 VGPR/lane; m = mt*16+lr, n = w*256+nt*16+lk*4+j — same swapped-MFMA
// mapping as gemm_nt). Then exp in-register, row-sum via shfl_xor(16,32)+LDS cross-wave reduce,
// scale, single fp32 write of attn, and per-(q mod 4) column sums via shfl_xor(4,8) + atomicAdd,
// exactly matching the old softcs cs[] semantics. Eliminates the 134 MB fp16 score write +
// 134 MB re-read of the old two-kernel path.
__global__ __launch_bounds__(256, 2) void fused_attn_kernel(
    const half_t* __restrict__ Tq, const half_t* __restrict__ Tk,
    float* __restrict__ attn, float* __restrict__ cs) {
  const int z = blockIdx.y;
  const int q0 = blockIdx.x * 32;
  const int t = threadIdx.x;
  const int w = t >> 6, lane = t & 63;
  const int lr = lane & 15, lk = lane >> 4;

  __shared__ half_t sQ[32 * 264];  // stride 264 halves (=528B): +8 pad kills the 512B-stride bank conflict
  __shared__ float sRS[4][32];

  // stage Tq[z][q0..q0+31][0..255] -> sQ (coalesced half8)
  const half_t* Tqz = Tq + (size_t)z * 262144 + (size_t)q0 * 256;
  for (int c = t; c < 1024; c += 256) {
    int row = c >> 5, col8 = (c & 31) * 8;
    *(half8*)&sQ[row * 264 + col8] = *(const half8*)&Tqz[row * 256 + col8];
  }
  __syncthreads();

  const half_t* Tkz = Tk + (size_t)z * 262144;
  const int nb = w * 256;

  floatx4 acc[2][16] = {};
  for (int k0 = 0; k0 < 256; k0 += 32) {
    half8 af0 = *(const half8*)&sQ[lr * 264 + k0 + lk * 8];
    half8 af1 = *(const half8*)&sQ[(16 + lr) * 264 + k0 + lk * 8];
#pragma unroll
    for (int nt = 0; nt < 16; ++nt) {
      half8 bf = *(const half8*)&Tkz[(size_t)(nb + nt * 16 + lr) * 256 + k0 + lk * 8];
      acc[0][nt] = __builtin_amdgcn_mfma_f32_16x16x32_f16(bf, af0, acc[0][nt], 0, 0, 0);
      acc[1][nt] = __builtin_amdgcn_mfma_f32_16x16x32_f16(bf, af1, acc[1][nt], 0, 0, 0);
    }
  }

  // exp (reference softmax has NO max-subtraction; scores are O(±3)) + per-lane partial row sums
  float rs0 = 0.0f, rs1 = 0.0f;
#pragma unroll
  for (int nt = 0; nt < 16; ++nt) {
#pragma unroll
    for (int j = 0; j < 4; ++j) {
      float v0 = __expf(acc[0][nt][j]);
      float v1 = __expf(acc[1][nt][j]);
      acc[0][nt][j] = v0; acc[1][nt][j] = v1;
      rs0 += v0; rs1 += v1;
    }
  }
  // reduce over lk (lanes lr, lr+16, lr+32, lr+48) -> wave's 256-col row sum
  rs0 += __shfl_xor(rs0, 16); rs0 += __shfl_xor(rs0, 32);
  rs1 += __shfl_xor(rs1, 16); rs1 += __shfl_xor(rs1, 32);
  if (lane < 16) { sRS[w][lane] = rs0; sRS[w][16 + lane] = rs1; }
  __syncthreads();
  float inv0 = 1.0f / (sRS[0][lr] + sRS[1][lr] + sRS[2][lr] + sRS[3][lr]);
  float inv1 = 1.0f / (sRS[0][16 + lr] + sRS[1][16 + lr] + sRS[2][16 + lr] + sRS[3][16 + lr]);

  float* attnz = attn + (size_t)z * 1048576;
  float* csz = cs + (size_t)z * 4096;
#pragma unroll
  for (int nt = 0; nt < 16; ++nt) {
    int n = nb + nt * 16 + lk * 4;
    float4 o0, o1;
    o0.x = acc[0][nt][0] * inv0; o0.y = acc[0][nt][1] * inv0;
    o0.z = acc[0][nt][2] * inv0; o0.w = acc[0][nt][3] * inv0;
    o1.x = acc[1][nt][0] * inv1; o1.y = acc[1][nt][1] * inv1;
    o1.z = acc[1][nt][2] * inv1; o1.w = acc[1][nt][3] * inv1;
    *(float4*)&attnz[(size_t)(q0 + lr) * 1024 + n] = o0;
    *(float4*)&attnz[(size_t)(q0 + 16 + lr) * 1024 + n] = o1;
    // column sums per r = q mod 4: rows lr and 16+lr share r = lr&3; sum the
    // 4 lanes {lr, lr^4, lr^8, lr^12} (same r, same lk) via shfl_xor(4,8)
    float c0 = o0.x + o1.x, c1 = o0.y + o1.y, c2 = o0.z + o1.z, c3 = o0.w + o1.w;
    c0 += __shfl_xor(c0, 4); c0 += __shfl_xor(c0, 8);
    c1 += __shfl_xor(c1, 4); c1 += __shfl_xor(c1, 8);
    c2 += __shfl_xor(c2, 4); c2 += __shfl_xor(c2, 8);
    c3 += __shfl_xor(c3, 4); c3 += __shfl_xor(c3, 8);
    if (lr < 4) {
      float* p = csz + (size_t)lr * 1024 + n;
      atomicAdd(p + 0, c0);
      atomicAdd(p + 1, c1);
      atomicAdd(p + 2, c2);
      atomicAdd(p + 3, c3);
    }
  }
}

// ---------------- abar[b, r*256+d] = (1/1024) sum_{h,k} cs[bh][r][k] * Tv[bh][k][d] ----------------
__global__ __launch_bounds__(256) void abar_kernel(const float* __restrict__ cs,
                                                   const half_t* __restrict__ Tv,
                                                   float* __restrict__ abar) {
  int b = blockIdx.x, r = blockIdx.y, kc = blockIdx.z;
  int d = threadIdx.x;
  __shared__ float scs[4][128];
  for (int idx = d; idx < 512; idx += 256) {
    int h = idx >> 7, k = idx & 127;
    scs[h][k] = cs[(size_t)(b * 4 + h) * 4096 + (size_t)r * 1024 + kc * 128 + k];
  }
  __syncthreads();
  float acc = 0.0f;
  for (int h = 0; h < 4; ++h) {
    const half_t* tv = Tv + (size_t)(b * 4 + h) * 262144 + (size_t)kc * 32768 + d;
#pragma unroll 4
    for (int k = 0; k < 128; ++k)
      acc += scs[h][k] * (float)tv[(size_t)k * 256];
  }
  atomicAdd(&abar[b * 1024 + r * 256 + d], acc * (1.0f / 1024.0f));
}

// ---------------- bcomb[j] = b1[j] + sum_k bo[k] * W1[k][j] ----------------
__global__ __launch_bounds__(256) void bcomb_kernel(const float* __restrict__ bo,
                                                    const float* __restrict__ W1,
                                                    const float* __restrict__ b1,
                                                    float* __restrict__ bcomb) {
  int t = threadIdx.x;
  int j = t & 127, h = t >> 7;
  float acc = 0.0f;
  for (int k = h * 1024; k < h * 1024 + 1024; ++k)
    acc += bo[k] * W1[(size_t)k * 128 + j];
  __shared__ float sm[2][128];
  sm[h][j] = acc;
  __syncthreads();
  if (t < 128) bcomb[t] = sm[0][t] + sm[1][t] + b1[t];
}

// ---------------- out[b][j] = bcomb[j] + sum_c abar[b][c] * Wcomb[c][j] ----------------
__global__ __launch_bounds__(256) void final2_kernel(const float* __restrict__ abar,
                                                     const half_t* __restrict__ Wcomb,
                                                     const float* __restrict__ bcomb,
                                                     float* __restrict__ out) {
  int b = blockIdx.x, t = threadIdx.x;
  int j = t & 127, h = t >> 7;
  __shared__ float sa[1024];
  __shared__ float sm[2][128];
  for (int i = t; i < 1024; i += 256) sa[i] = abar[(size_t)b * 1024 + i];
  __syncthreads();
  float acc = 0.0f;
  for (int c = h * 512; c < h * 512 + 512; ++c)
    acc += sa[c] * (float)Wcomb[(size_t)c * 128 + j];
  sm[h][j] = acc;
  __syncthreads();
  if (t < 128) out[(size_t)b * 128 + t] = sm[0][t] + sm[1][t] + bcomb[t];
}

extern "C" void kernel_launch(void* const* d_in, const int* in_sizes, int n_in,
                              void* d_out, int out_size, void* d_ws, size_t ws_size,
                              hipStream_t stream) {
  const float* query = (const float*)d_in[0];
  const float* key   = (const float*)d_in[1];
  const float* value = (const float*)d_in[2];
  const float* Wq = (const float*)d_in[3];
  const float* bq = (const float*)d_in[4];
  const float* Wk = (const float*)d_in[5];
  const float* bk = (const float*)d_in[6];
  const float* Wv = (const float*)d_in[7];
  const float* bv = (const float*)d_in[8];
  const float* Wo = (const float*)d_in[9];
  const float* bo = (const float*)d_in[10];
  const float* W1 = (const float*)d_in[11];
  const float* b1 = (const float*)d_in[12];

  // workspace layout (bytes)
  char* ws = (char*)d_ws;
  half_t* Tq   = (half_t*)(ws + 0);          // 16M halves  [b][s][1024]  (dead after fused kernel)
  half_t* Tk   = (half_t*)(ws + 33554432);   // 16M halves
  half_t* Tv   = (half_t*)(ws + 67108864);   // 16M halves  (live until abar)
  float*  cs   = (float*)(ws + 100663296);   // [64][4][1024] f32
  float*  abar = (float*)(ws + 101711872);   // [16][1024] f32
  half_t* Wqt  = (half_t*)(ws + 101777408);  // [1024][128] f16
  half_t* Wkt  = (half_t*)(ws + 102039552);  // [1024][256] f16
  half_t* Wvt  = (half_t*)(ws + 102563840);  // [1024][256] f16
  // overlapped onto dead Tq region (only used after the fused attention kernel):
  half_t* W1t   = (half_t*)(ws + 0);         // [128][2048] f16
  half_t* Wcomb = (half_t*)(ws + 524288);    // [1024][128] f16
  float*  bcomb = (float*)(ws + 786432);     // [128] f32

  float* out  = (float*)d_out;
  float* attn = out + 2048;  // [64][1024][1024] f32

  hipMemsetAsync(cs, 0, 1048576 + 65536, stream);  // zero cs + abar

  wtrans_kernel<<<dim3(32, 4), 256, 0, stream>>>(Wq, Wqt, 128, 1024);
  wtrans_kernel<<<dim3(32, 8), 256, 0, stream>>>(Wk, Wkt, 256, 1024);
  wtrans_kernel<<<dim3(32, 8), 256, 0, stream>>>(Wv, Wvt, 256, 1024);

  // projections: T = X @ W + b  (fp32 A staged->fp16, fp16 out)
  gemm_nt<true, true><<<dim3(128, 8, 1), 256, 0, stream>>>(query, nullptr, Wqt, bq, Tq, 128, 1024, 0, 0, 0);
  gemm_nt<true, true><<<dim3(128, 8, 1), 256, 0, stream>>>(key,   nullptr, Wkt, bk, Tk, 256, 1024, 0, 0, 0);
  gemm_nt<true, true><<<dim3(128, 8, 1), 256, 0, stream>>>(value, nullptr, Wvt, bv, Tv, 256, 1024, 0, 0, 0);

  // fused: scores + softmax + fp32 attn write + per-(q%4) column sums
  fused_attn_kernel<<<dim3(32, 64), 256, 0, stream>>>(Tq, Tk, attn, cs);

  // Wcomb = Wo @ W1 (folded tail GEMM), bcomb = bo @ W1 + b1 -- Tq region is dead now
  wtrans_kernel<<<dim3(4, 64), 256, 0, stream>>>(W1, W1t, 2048, 128);
  gemm_nt<true, false><<<dim3(8, 1, 1), 256, 0, stream>>>(Wo, nullptr, W1t, nullptr, Wcomb, 2048, 128, 0, 0, 0);
  bcomb_kernel<<<1, 256, 0, stream>>>(bo, W1, b1, bcomb);

  abar_kernel<<<dim3(16, 4, 8), 256, 0, stream>>>(cs, Tv, abar);
  final2_kernel<<<16, 256, 0, stream>>>(abar, Wcomb, bcomb, out);
}

// Round 4
// 735.943 us; speedup vs baseline: 1.0986x; 1.0986x over previous
//
#include <hip/hip_runtime.h>
#include <hip/hip_bf16.h>

typedef _Float16 half_t;
typedef _Float16 half8 __attribute__((ext_vector_type(8)));
typedef _Float16 half4v __attribute__((ext_vector_type(4)));
typedef float floatx4 __attribute__((ext_vector_type(4)));

// ---------------- weight transpose + fp32->fp16: Wt[n][k] = W[k][n], W is [K][N] ----------------
__global__ __launch_bounds__(256) void wtrans_kernel(const float* __restrict__ W,
                                                     half_t* __restrict__ Wt, int K, int N) {
  __shared__ float sm[32][33];
  int n0 = blockIdx.x * 32, k0 = blockIdx.y * 32;
  int x = threadIdx.x & 31, y0 = threadIdx.x >> 5;
#pragma unroll
  for (int yy = 0; yy < 4; ++yy) {
    int y = y0 + yy * 8;
    sm[y][x] = W[(size_t)(k0 + y) * N + n0 + x];
  }
  __syncthreads();
#pragma unroll
  for (int yy = 0; yy < 4; ++yy) {
    int y = y0 + yy * 8;
    Wt[(size_t)(n0 + y) * K + k0 + x] = (half_t)sm[x][y];
  }
}

// ---------------- NT GEMM: C[m][n] = sum_k A[m][k]*Bt[n][k] (+bias[n]), fp16 MFMA, fp32 acc ----------------
// tile 128x128, BK=32, 256 threads = 4 waves in 2x2, each wave 64x64 via 4x4 of 16x16x32 MFMA.
// MFMA operands SWAPPED (mfma(bf, af)): lane then owns 4 consecutive n of one row m.
template <bool AF32, bool BIAS>
__global__ __launch_bounds__(256) void gemm_nt(
    const float* __restrict__ Af, const half_t* __restrict__ Ah,
    const half_t* __restrict__ Bt, const float* __restrict__ bias,
    half_t* __restrict__ C, int K, int ldc,
    size_t aStrideZ, size_t bStrideZ, size_t cStrideZ) {
  __shared__ half_t sA[128 * 32];
  __shared__ half_t sB[128 * 32];
  const int t = threadIdx.x;
  const int m0 = blockIdx.x * 128;
  const int n0 = blockIdx.y * 128;
  const int z = blockIdx.z;
  const half_t* Bz = Bt + bStrideZ * (size_t)z;
  const int w = t >> 6, lane = t & 63;
  const int wm = w & 1, wn = w >> 1;
  const int lr = lane & 15, lk = lane >> 4;
  const int srow = t >> 2, sg = t & 3;

  floatx4 acc[4][4] = {};

  for (int k0 = 0; k0 < K; k0 += 32) {
    __syncthreads();
#pragma unroll
    for (int rep = 0; rep < 2; ++rep) {
      int row = srow + rep * 64;
      int goff = (sg ^ ((row >> 1) & 3)) * 8;
      half8 hv;
      if constexpr (AF32) {
        const float* p = Af + (size_t)(m0 + row) * K + k0 + sg * 8;
        float4 f0 = *(const float4*)p;
        float4 f1 = *(const float4*)(p + 4);
        hv[0] = (half_t)f0.x; hv[1] = (half_t)f0.y;
        hv[2] = (half_t)f0.z; hv[3] = (half_t)f0.w;
        hv[4] = (half_t)f1.x; hv[5] = (half_t)f1.y;
        hv[6] = (half_t)f1.z; hv[7] = (half_t)f1.w;
      } else {
        const half_t* p = Ah + aStrideZ * (size_t)z + (size_t)(m0 + row) * K + k0 + sg * 8;
        hv = *(const half8*)p;
      }
      *(half8*)&sA[row * 32 + goff] = hv;
      const half_t* q = Bz + (size_t)(n0 + row) * K + k0 + sg * 8;
      *(half8*)&sB[row * 32 + goff] = *(const half8*)q;
    }
    __syncthreads();
    half8 af[4], bf[4];
#pragma unroll
    for (int mt = 0; mt < 4; ++mt) {
      int row = wm * 64 + mt * 16 + lr;
      af[mt] = *(const half8*)&sA[row * 32 + ((lk ^ ((row >> 1) & 3)) * 8)];
    }
#pragma unroll
    for (int nt = 0; nt < 4; ++nt) {
      int row = wn * 64 + nt * 16 + lr;
      bf[nt] = *(const half8*)&sB[row * 32 + ((lk ^ ((row >> 1) & 3)) * 8)];
    }
#pragma unroll
    for (int mt = 0; mt < 4; ++mt)
#pragma unroll
      for (int nt = 0; nt < 4; ++nt)
        acc[mt][nt] = __builtin_amdgcn_mfma_f32_16x16x32_f16(bf[nt], af[mt], acc[mt][nt], 0, 0, 0);
  }

  half_t* Cz = C + cStrideZ * (size_t)z;
#pragma unroll
  for (int mt = 0; mt < 4; ++mt) {
    int m = m0 + wm * 64 + mt * 16 + lr;
#pragma unroll
    for (int nt = 0; nt < 4; ++nt) {
      int nb = n0 + wn * 64 + nt * 16 + lk * 4;
      floatx4 a = acc[mt][nt];
      half4v h;
      if constexpr (BIAS) {
        float4 bv = *(const float4*)&bias[nb];
        h[0] = (half_t)(a[0] + bv.x); h[1] = (half_t)(a[1] + bv.y);
        h[2] = (half_t)(a[2] + bv.z); h[3] = (half_t)(a[3] + bv.w);
      } else {
        h[0] = (half_t)a[0]; h[1] = (half_t)a[1];
        h[2] = (half_t)a[2]; h[3] = (half_t)a[3];
      }
      *(half4v*)&Cz[(size_t)m * ldc + nb] = h;
    }
  }
}

// ---------------- FUSED scores GEMM + softmax + column sums ----------------
// grid (32 qblocks, 64 z), 256 thr = 4 waves. Block computes S = Tq[z][q0:q0+32][:] @ Tk[z]^T
// (32 x 1024, K=256) in fp32 MFMA accumulators; wave w owns cols [w*256,(w+1)*256).
// Round-2 fix: Tk is now staged through double-buffered, XOR-swizzled LDS tiles (the proven
// gemm_nt pattern) instead of per-lane global loads inside the MFMA loop -- the counters
// showed MfmaUtil 5% / VALUBusy 7% / HBM 25% (pure latency-bound). 32 stages of (g,k0):
// each stage stages 256 rows x 32 halves = 16 KB for stage s+1 while MFMAing stage s.
// Fully unrolled so acc indices stay compile-time (runtime-indexed ext_vector -> scratch).
__global__ __launch_bounds__(256, 2) void fused_attn_kernel(
    const half_t* __restrict__ Tq, const half_t* __restrict__ Tk,
    float* __restrict__ attn, float* __restrict__ cs) {
  const int z = blockIdx.y;
  const int q0 = blockIdx.x * 32;
  const int t = threadIdx.x;
  const int w = t >> 6, lane = t & 63;
  const int lr = lane & 15, lk = lane >> 4;
  const int srow = t >> 2, sg = t & 3;

  __shared__ half_t sQ[32 * 264];       // stride 264 halves: kills 512B-stride bank conflict
  __shared__ half_t sK[2][256 * 32];    // double-buffered Tk chunk, gemm_nt XOR-swizzle
  __shared__ float sRS[4][32];

  // stage Tq[z][q0..q0+31][0..255] -> sQ (coalesced half8)
  const half_t* Tqz = Tq + (size_t)z * 262144 + (size_t)q0 * 256;
  for (int c = t; c < 1024; c += 256) {
    int row = c >> 5, col8 = (c & 31) * 8;
    *(half8*)&sQ[row * 264 + col8] = *(const half8*)&Tqz[row * 256 + col8];
  }

  const half_t* Tkz = Tk + (size_t)z * 262144;

  // chunk (g,k0): LDS slot sl (0..255) holds global Tk row (sl>>6)*256 + g*64 + (sl&63),
  // k-range [k0*32, k0*32+32). Thread t stages slots rep*64+srow (rep=0..3), quarter sg.
  // Swizzle: content k-group (sg ^ ((sl>>1)&3)) stored at LDS k-group sg (involution).
  half8 st[4];
  {
    // prologue: stage chunk for s=0 (g=0,k0=0)
#pragma unroll
    for (int rep = 0; rep < 4; ++rep) {
      int sl = rep * 64 + srow;
      int grow = rep * 256 + srow;  // g=0
      st[rep] = *(const half8*)&Tkz[(size_t)grow * 256 + ((sg ^ ((sl >> 1) & 3)) * 8)];
    }
#pragma unroll
    for (int rep = 0; rep < 4; ++rep) {
      int sl = rep * 64 + srow;
      *(half8*)&sK[0][sl * 32 + sg * 8] = st[rep];
    }
  }
  __syncthreads();

  floatx4 acc[2][16] = {};
#pragma unroll
  for (int s = 0; s < 32; ++s) {
    const int cur = s & 1;
    // issue global loads for stage s+1 (latency hides under this stage's ds_read+MFMA)
    if (s + 1 < 32) {
      const int gn = (s + 1) >> 3, k0n = (s + 1) & 7;
#pragma unroll
      for (int rep = 0; rep < 4; ++rep) {
        int sl = rep * 64 + srow;
        int grow = rep * 256 + gn * 64 + srow;
        st[rep] = *(const half8*)&Tkz[(size_t)grow * 256 + k0n * 32 + ((sg ^ ((sl >> 1) & 3)) * 8)];
      }
    }
    // compute on cur: nt = g*4+l, k-step k0s
    const int g = s >> 3, k0s = s & 7;
    half8 af0 = *(const half8*)&sQ[lr * 264 + k0s * 32 + lk * 8];
    half8 af1 = *(const half8*)&sQ[(16 + lr) * 264 + k0s * 32 + lk * 8];
#pragma unroll
    for (int l = 0; l < 4; ++l) {
      int sl = w * 64 + l * 16 + lr;
      half8 bf = *(const half8*)&sK[cur][sl * 32 + ((lk ^ ((sl >> 1) & 3)) * 8)];
      acc[0][g * 4 + l] = __builtin_amdgcn_mfma_f32_16x16x32_f16(bf, af0, acc[0][g * 4 + l], 0, 0, 0);
      acc[1][g * 4 + l] = __builtin_amdgcn_mfma_f32_16x16x32_f16(bf, af1, acc[1][g * 4 + l], 0, 0, 0);
    }
    // write next buffer (different buffer than reads above -> no intra-stage hazard;
    // single barrier per stage covers both cross-stage hazards)
    if (s + 1 < 32) {
#pragma unroll
      for (int rep = 0; rep < 4; ++rep) {
        int sl = rep * 64 + srow;
        *(half8*)&sK[cur ^ 1][sl * 32 + sg * 8] = st[rep];
      }
      __syncthreads();
    }
  }

  // exp (reference softmax has NO max-subtraction; scores are O(±3)) + per-lane partial row sums
  float rs0 = 0.0f, rs1 = 0.0f;
#pragma unroll
  for (int nt = 0; nt < 16; ++nt) {
#pragma unroll
    for (int j = 0; j < 4; ++j) {
      float v0 = __expf(acc[0][nt][j]);
      float v1 = __expf(acc[1][nt][j]);
      acc[0][nt][j] = v0; acc[1][nt][j] = v1;
      rs0 += v0; rs1 += v1;
    }
  }
  // reduce over lk (lanes lr, lr+16, lr+32, lr+48) -> wave's 256-col row sum
  rs0 += __shfl_xor(rs0, 16); rs0 += __shfl_xor(rs0, 32);
  rs1 += __shfl_xor(rs1, 16); rs1 += __shfl_xor(rs1, 32);
  if (lane < 16) { sRS[w][lane] = rs0; sRS[w][16 + lane] = rs1; }
  __syncthreads();
  float inv0 = 1.0f / (sRS[0][lr] + sRS[1][lr] + sRS[2][lr] + sRS[3][lr]);
  float inv1 = 1.0f / (sRS[0][16 + lr] + sRS[1][16 + lr] + sRS[2][16 + lr] + sRS[3][16 + lr]);

  const int nb = w * 256;
  float* attnz = attn + (size_t)z * 1048576;
  float* csz = cs + (size_t)z * 4096;
#pragma unroll
  for (int nt = 0; nt < 16; ++nt) {
    int n = nb + nt * 16 + lk * 4;
    float4 o0, o1;
    o0.x = acc[0][nt][0] * inv0; o0.y = acc[0][nt][1] * inv0;
    o0.z = acc[0][nt][2] * inv0; o0.w = acc[0][nt][3] * inv0;
    o1.x = acc[1][nt][0] * inv1; o1.y = acc[1][nt][1] * inv1;
    o1.z = acc[1][nt][2] * inv1; o1.w = acc[1][nt][3] * inv1;
    *(float4*)&attnz[(size_t)(q0 + lr) * 1024 + n] = o0;
    *(float4*)&attnz[(size_t)(q0 + 16 + lr) * 1024 + n] = o1;
    // column sums per r = q mod 4: rows lr and 16+lr share r = lr&3; sum the
    // 4 lanes {lr, lr^4, lr^8, lr^12} (same r, same lk) via shfl_xor(4,8)
    float c0 = o0.x + o1.x, c1 = o0.y + o1.y, c2 = o0.z + o1.z, c3 = o0.w + o1.w;
    c0 += __shfl_xor(c0, 4); c0 += __shfl_xor(c0, 8);
    c1 += __shfl_xor(c1, 4); c1 += __shfl_xor(c1, 8);
    c2 += __shfl_xor(c2, 4); c2 += __shfl_xor(c2, 8);
    c3 += __shfl_xor(c3, 4); c3 += __shfl_xor(c3, 8);
    if (lr < 4) {
      float* p = csz + (size_t)lr * 1024 + n;
      atomicAdd(p + 0, c0);
      atomicAdd(p + 1, c1);
      atomicAdd(p + 2, c2);
      atomicAdd(p + 3, c3);
    }
  }
}

// ---------------- abar[b, r*256+d] = (1/1024) sum_{h,k} cs[bh][r][k] * Tv[bh][k][d] ----------------
__global__ __launch_bounds__(256) void abar_kernel(const float* __restrict__ cs,
                                                   const half_t* __restrict__ Tv,
                                                   float* __restrict__ abar) {
  int b = blockIdx.x, r = blockIdx.y, kc = blockIdx.z;
  int d = threadIdx.x;
  __shared__ float scs[4][128];
  for (int idx = d; idx < 512; idx += 256) {
    int h = idx >> 7, k = idx & 127;
    scs[h][k] = cs[(size_t)(b * 4 + h) * 4096 + (size_t)r * 1024 + kc * 128 + k];
  }
  __syncthreads();
  float acc = 0.0f;
  for (int h = 0; h < 4; ++h) {
    const half_t* tv = Tv + (size_t)(b * 4 + h) * 262144 + (size_t)kc * 32768 + d;
#pragma unroll 4
    for (int k = 0; k < 128; ++k)
      acc += scs[h][k] * (float)tv[(size_t)k * 256];
  }
  atomicAdd(&abar[b * 1024 + r * 256 + d], acc * (1.0f / 1024.0f));
}

// ---------------- bcomb[j] = b1[j] + sum_k bo[k] * W1[k][j] ----------------
__global__ __launch_bounds__(256) void bcomb_kernel(const float* __restrict__ bo,
                                                    const float* __restrict__ W1,
                                                    const float* __restrict__ b1,
                                                    float* __restrict__ bcomb) {
  int t = threadIdx.x;
  int j = t & 127, h = t >> 7;
  float acc = 0.0f;
  for (int k = h * 1024; k < h * 1024 + 1024; ++k)
    acc += bo[k] * W1[(size_t)k * 128 + j];
  __shared__ float sm[2][128];
  sm[h][j] = acc;
  __syncthreads();
  if (t < 128) bcomb[t] = sm[0][t] + sm[1][t] + b1[t];
}

// ---------------- out[b][j] = bcomb[j] + sum_c abar[b][c] * Wcomb[c][j] ----------------
__global__ __launch_bounds__(256) void final2_kernel(const float* __restrict__ abar,
                                                     const half_t* __restrict__ Wcomb,
                                                     const float* __restrict__ bcomb,
                                                     float* __restrict__ out) {
  int b = blockIdx.x, t = threadIdx.x;
  int j = t & 127, h = t >> 7;
  __shared__ float sa[1024];
  __shared__ float sm[2][128];
  for (int i = t; i < 1024; i += 256) sa[i] = abar[(size_t)b * 1024 + i];
  __syncthreads();
  float acc = 0.0f;
  for (int c = h * 512; c < h * 512 + 512; ++c)
    acc += sa[c] * (float)Wcomb[(size_t)c * 128 + j];
  sm[h][j] = acc;
  __syncthreads();
  if (t < 128) out[(size_t)b * 128 + t] = sm[0][t] + sm[1][t] + bcomb[t];
}

extern "C" void kernel_launch(void* const* d_in, const int* in_sizes, int n_in,
                              void* d_out, int out_size, void* d_ws, size_t ws_size,
                              hipStream_t stream) {
  const float* query = (const float*)d_in[0];
  const float* key   = (const float*)d_in[1];
  const float* value = (const float*)d_in[2];
  const float* Wq = (const float*)d_in[3];
  const float* bq = (const float*)d_in[4];
  const float* Wk = (const float*)d_in[5];
  const float* bk = (const float*)d_in[6];
  const float* Wv = (const float*)d_in[7];
  const float* bv = (const float*)d_in[8];
  const float* Wo = (const float*)d_in[9];
  const float* bo = (const float*)d_in[10];
  const float* W1 = (const float*)d_in[11];
  const float* b1 = (const float*)d_in[12];

  // workspace layout (bytes)
  char* ws = (char*)d_ws;
  half_t* Tq   = (half_t*)(ws + 0);          // 16M halves  [b][s][1024]  (dead after fused kernel)
  half_t* Tk   = (half_t*)(ws + 33554432);   // 16M halves
  half_t* Tv   = (half_t*)(ws + 67108864);   // 16M halves  (live until abar)
  float*  cs   = (float*)(ws + 100663296);   // [64][4][1024] f32
  float*  abar = (float*)(ws + 101711872);   // [16][1024] f32
  half_t* Wqt  = (half_t*)(ws + 101777408);  // [1024][128] f16
  half_t* Wkt  = (half_t*)(ws + 102039552);  // [1024][256] f16
  half_t* Wvt  = (half_t*)(ws + 102563840);  // [1024][256] f16
  // overlapped onto dead Tq region (only used after the fused attention kernel):
  half_t* W1t   = (half_t*)(ws + 0);         // [128][2048] f16
  half_t* Wcomb = (half_t*)(ws + 524288);    // [1024][128] f16
  float*  bcomb = (float*)(ws + 786432);     // [128] f32

  float* out  = (float*)d_out;
  float* attn = out + 2048;  // [64][1024][1024] f32

  hipMemsetAsync(cs, 0, 1048576 + 65536, stream);  // zero cs + abar

  wtrans_kernel<<<dim3(32, 4), 256, 0, stream>>>(Wq, Wqt, 128, 1024);
  wtrans_kernel<<<dim3(32, 8), 256, 0, stream>>>(Wk, Wkt, 256, 1024);
  wtrans_kernel<<<dim3(32, 8), 256, 0, stream>>>(Wv, Wvt, 256, 1024);

  // projections: T = X @ W + b  (fp32 A staged->fp16, fp16 out)
  gemm_nt<true, true><<<dim3(128, 8, 1), 256, 0, stream>>>(query, nullptr, Wqt, bq, Tq, 128, 1024, 0, 0, 0);
  gemm_nt<true, true><<<dim3(128, 8, 1), 256, 0, stream>>>(key,   nullptr, Wkt, bk, Tk, 256, 1024, 0, 0, 0);
  gemm_nt<true, true><<<dim3(128, 8, 1), 256, 0, stream>>>(value, nullptr, Wvt, bv, Tv, 256, 1024, 0, 0, 0);

  // fused: scores + softmax + fp32 attn write + per-(q%4) column sums
  fused_attn_kernel<<<dim3(32, 64), 256, 0, stream>>>(Tq, Tk, attn, cs);

  // Wcomb = Wo @ W1 (folded tail GEMM), bcomb = bo @ W1 + b1 -- Tq region is dead now
  wtrans_kernel<<<dim3(4, 64), 256, 0, stream>>>(W1, W1t, 2048, 128);
  gemm_nt<true, false><<<dim3(8, 1, 1), 256, 0, stream>>>(Wo, nullptr, W1t, nullptr, Wcomb, 2048, 128, 0, 0, 0);
  bcomb_kernel<<<1, 256, 0, stream>>>(bo, W1, b1, bcomb);

  abar_kernel<<<dim3(16, 4, 8), 256, 0, stream>>>(cs, Tv, abar);
  final2_kernel<<<16, 256, 0, stream>>>(abar, Wcomb, bcomb, out);
}

// Round 6
// 712.762 us; speedup vs baseline: 1.1343x; 1.0325x over previous
//
#include <hip/hip_runtime.h>
#include <hip/hip_bf16.h>

typedef _Float16 half_t;
typedef _Float16 half8 __attribute__((ext_vector_type(8)));
typedef _Float16 half4v __attribute__((ext_vector_type(4)));
typedef float floatx4 __attribute__((ext_vector_type(4)));

// direct global->LDS DMA, 16B per lane; lds ptr must be wave-uniform (HW writes base+lane*16)
__device__ inline void gload16(const half_t* g, half_t* l) {
  __builtin_amdgcn_global_load_lds(
      (const __attribute__((address_space(1))) void*)g,
      (__attribute__((address_space(3))) void*)l, 16, 0, 0);
}

// ---------------- weight transpose + fp32->fp16: Wt[n][k] = W[k][n], W is [K][N] ----------------
__global__ __launch_bounds__(256) void wtrans_kernel(const float* __restrict__ W,
                                                     half_t* __restrict__ Wt, int K, int N) {
  __shared__ float sm[32][33];
  int n0 = blockIdx.x * 32, k0 = blockIdx.y * 32;
  int x = threadIdx.x & 31, y0 = threadIdx.x >> 5;
#pragma unroll
  for (int yy = 0; yy < 4; ++yy) {
    int y = y0 + yy * 8;
    sm[y][x] = W[(size_t)(k0 + y) * N + n0 + x];
  }
  __syncthreads();
#pragma unroll
  for (int yy = 0; yy < 4; ++yy) {
    int y = y0 + yy * 8;
    Wt[(size_t)(n0 + y) * K + k0 + x] = (half_t)sm[x][y];
  }
}

// ---------------- NT GEMM: C[m][n] = sum_k A[m][k]*Bt[n][k] (+bias[n]), fp16 MFMA, fp32 acc ----------------
template <bool AF32, bool BIAS>
__global__ __launch_bounds__(256) void gemm_nt(
    const float* __restrict__ Af, const half_t* __restrict__ Ah,
    const half_t* __restrict__ Bt, const float* __restrict__ bias,
    half_t* __restrict__ C, int K, int ldc,
    size_t aStrideZ, size_t bStrideZ, size_t cStrideZ) {
  __shared__ half_t sA[128 * 32];
  __shared__ half_t sB[128 * 32];
  const int t = threadIdx.x;
  const int m0 = blockIdx.x * 128;
  const int n0 = blockIdx.y * 128;
  const int z = blockIdx.z;
  const half_t* Bz = Bt + bStrideZ * (size_t)z;
  const int w = t >> 6, lane = t & 63;
  const int wm = w & 1, wn = w >> 1;
  const int lr = lane & 15, lk = lane >> 4;
  const int srow = t >> 2, sg = t & 3;

  floatx4 acc[4][4] = {};

  for (int k0 = 0; k0 < K; k0 += 32) {
    __syncthreads();
#pragma unroll
    for (int rep = 0; rep < 2; ++rep) {
      int row = srow + rep * 64;
      int goff = (sg ^ ((row >> 1) & 3)) * 8;
      half8 hv;
      if constexpr (AF32) {
        const float* p = Af + (size_t)(m0 + row) * K + k0 + sg * 8;
        float4 f0 = *(const float4*)p;
        float4 f1 = *(const float4*)(p + 4);
        hv[0] = (half_t)f0.x; hv[1] = (half_t)f0.y;
        hv[2] = (half_t)f0.z; hv[3] = (half_t)f0.w;
        hv[4] = (half_t)f1.x; hv[5] = (half_t)f1.y;
        hv[6] = (half_t)f1.z; hv[7] = (half_t)f1.w;
      } else {
        const half_t* p = Ah + aStrideZ * (size_t)z + (size_t)(m0 + row) * K + k0 + sg * 8;
        hv = *(const half8*)p;
      }
      *(half8*)&sA[row * 32 + goff] = hv;
      const half_t* q = Bz + (size_t)(n0 + row) * K + k0 + sg * 8;
      *(half8*)&sB[row * 32 + goff] = *(const half8*)q;
    }
    __syncthreads();
    half8 af[4], bf[4];
#pragma unroll
    for (int mt = 0; mt < 4; ++mt) {
      int row = wm * 64 + mt * 16 + lr;
      af[mt] = *(const half8*)&sA[row * 32 + ((lk ^ ((row >> 1) & 3)) * 8)];
    }
#pragma unroll
    for (int nt = 0; nt < 4; ++nt) {
      int row = wn * 64 + nt * 16 + lr;
      bf[nt] = *(const half8*)&sB[row * 32 + ((lk ^ ((row >> 1) & 3)) * 8)];
    }
#pragma unroll
    for (int mt = 0; mt < 4; ++mt)
#pragma unroll
      for (int nt = 0; nt < 4; ++nt)
        acc[mt][nt] = __builtin_amdgcn_mfma_f32_16x16x32_f16(bf[nt], af[mt], acc[mt][nt], 0, 0, 0);
  }

  half_t* Cz = C + cStrideZ * (size_t)z;
#pragma unroll
  for (int mt = 0; mt < 4; ++mt) {
    int m = m0 + wm * 64 + mt * 16 + lr;
#pragma unroll
    for (int nt = 0; nt < 4; ++nt) {
      int nb = n0 + wn * 64 + nt * 16 + lk * 4;
      floatx4 a = acc[mt][nt];
      half4v h;
      if constexpr (BIAS) {
        float4 bv = *(const float4*)&bias[nb];
        h[0] = (half_t)(a[0] + bv.x); h[1] = (half_t)(a[1] + bv.y);
        h[2] = (half_t)(a[2] + bv.z); h[3] = (half_t)(a[3] + bv.w);
      } else {
        h[0] = (half_t)a[0]; h[1] = (half_t)a[1];
        h[2] = (half_t)a[2]; h[3] = (half_t)a[3];
      }
      *(half4v*)&Cz[(size_t)m * ldc + nb] = h;
    }
  }
}

// ---------------- FUSED scores GEMM + softmax + column sums ----------------
// grid (32 qblocks, 64 z), 256 thr = 4 waves. Block computes S = Tq[z][q0:q0+32][:] @ Tk[z]^T
// (32 x 1024, K=256) in fp32 MFMA acc; wave w owns cols [w*256,(w+1)*256).
// Round-4 analysis: occupancy is register-capped at 2 waves/SIMD (112 VGPR + 128 AGPR acc), and
// the reg-staged LDS pipeline had 2 drain points/stage -> bytes-in-flight/CU far below the
// Little's-law requirement (kernel streamed at 2.6 TB/s, 41% of achievable, with all pipes idle).
// Round-5 fix: global_load_lds (16B) direct-to-LDS with pre-swizzled GLOBAL source + linear LDS
// dest; triple-buffered sK; counted s_waitcnt vmcnt(4) + raw s_barrier per stage (never drain to
// 0 in-loop). Keeps {S(s+1),S(s+2)} = 8 loads/wave (~64KB/CU) in flight under every compute phase.
// Hazard ledger (1 barrier/stage, buffers s%3): each wave's vmcnt(4) retires its own S(s) loads
// BEFORE s_barrier -> after B_s all waves' S(s) data resident (cross-wave safe). Stage-s readers
// of buf[s%3] finish (lgkmcnt before MFMA use) before that wave reaches B_{s+1}; S(s+3) (same
// buffer) is issued after B_{s+1} -> WAR safe. S(s+2) issued after B_s targets buf[(s+2)%3],
// whose last readers (stage s-1) drained before B_s -> safe.
__global__ __launch_bounds__(256, 2) void fused_attn_kernel(
    const half_t* __restrict__ Tq, const half_t* __restrict__ Tk,
    float* __restrict__ attn, float* __restrict__ cs) {
  const int z = blockIdx.y;
  const int q0 = blockIdx.x * 32;
  const int t = threadIdx.x;
  const int w = t >> 6, lane = t & 63;
  const int lr = lane & 15, lk = lane >> 4;

  __shared__ half_t sQ[32 * 256];     // linear; XOR-swizzled content (j8 ^= row&7), no pad
  __shared__ half_t sK[3][256 * 32];  // triple-buffered Tk chunks, gemm_nt XOR-swizzle content
  __shared__ float sRS[4][32];

  const half_t* Tqz = Tq + (size_t)z * 262144 + (size_t)q0 * 256;
  const half_t* Tkz = Tk + (size_t)z * 262144;

  // ---- prologue: issue sQ + S(0) + S(1) via global_load_lds (12 insts/wave in flight) ----
  // sQ: LDS half-pos i*8 (i = r*256 + w*64 + lane) holds Q[row][(j8 ^ (row&7))*8], row=i>>5, j8=i&31
#pragma unroll
  for (int r = 0; r < 4; ++r) {
    int i = r * 256 + w * 64 + lane;
    int row = i >> 5, j8 = i & 31;
    gload16(Tqz + (size_t)row * 256 + ((j8 ^ (row & 7)) * 8), &sQ[(r * 256 + w * 64) * 8]);
  }
  // sK chunk for stage sp: LDS half-pos i*8 holds Tk[grow(sl)][ks*32 + (kg^((sl>>1)&3))*8],
  // sl=i>>2, kg=i&3, grow(sl)=(sl>>6)*256 + g*64 + (sl&63)  (wave w consumes sl in [w*64,w*64+64))
#pragma unroll
  for (int sp = 0; sp < 2; ++sp) {
#pragma unroll
    for (int r = 0; r < 4; ++r) {
      int i = r * 256 + w * 64 + lane;
      int sl = i >> 2, kg = i & 3;
      int grow = ((sl >> 6) << 8) + (sl & 63);  // g=0 for sp<8
      gload16(Tkz + (size_t)grow * 256 + sp * 32 + ((kg ^ ((sl >> 1) & 3)) * 8),
              &sK[sp][(r * 256 + w * 64) * 8]);
    }
  }

  floatx4 acc[2][16] = {};
#pragma unroll
  for (int s = 0; s < 32; ++s) {
    // retire stage-s loads only; keep S(s+1) (and soon S(s+2)) in flight
    if (s < 31) {
      asm volatile("s_waitcnt vmcnt(4)" ::: "memory");
    } else {
      asm volatile("s_waitcnt vmcnt(0)" ::: "memory");
    }
    __builtin_amdgcn_sched_barrier(0);
    __builtin_amdgcn_s_barrier();

    // issue S(s+2) (after the barrier: its target buffer's last readers have drained)
    if (s + 2 < 32) {
      const int sp = s + 2, g2 = sp >> 3, ks2 = sp & 7;
      half_t* base = &sK[sp % 3][0];
#pragma unroll
      for (int r = 0; r < 4; ++r) {
        int i = r * 256 + w * 64 + lane;
        int sl = i >> 2, kg = i & 3;
        int grow = ((sl >> 6) << 8) + g2 * 64 + (sl & 63);
        gload16(Tkz + (size_t)grow * 256 + ks2 * 32 + ((kg ^ ((sl >> 1) & 3)) * 8),
                base + (r * 256 + w * 64) * 8);
      }
    }

    // compute on buf[s%3]: nt = g*4+l, k-step ks
    const int g = s >> 3, ks = s & 7;
    const half_t* kb = &sK[s % 3][0];
    const int j8 = ((ks * 4 + lk) ^ (lr & 7)) * 8;  // (16+lr)&7 == lr&7, same j8 for both rows
    half8 af0 = *(const half8*)&sQ[lr * 256 + j8];
    half8 af1 = *(const half8*)&sQ[(16 + lr) * 256 + j8];
#pragma unroll
    for (int l = 0; l < 4; ++l) {
      int sl = w * 64 + l * 16 + lr;
      half8 bf = *(const half8*)&kb[sl * 32 + ((lk ^ ((sl >> 1) & 3)) * 8)];
      acc[0][g * 4 + l] = __builtin_amdgcn_mfma_f32_16x16x32_f16(bf, af0, acc[0][g * 4 + l], 0, 0, 0);
      acc[1][g * 4 + l] = __builtin_amdgcn_mfma_f32_16x16x32_f16(bf, af1, acc[1][g * 4 + l], 0, 0, 0);
    }
  }

  // exp (reference softmax has NO max-subtraction; scores are O(±3)) + per-lane partial row sums
  float rs0 = 0.0f, rs1 = 0.0f;
#pragma unroll
  for (int nt = 0; nt < 16; ++nt) {
#pragma unroll
    for (int j = 0; j < 4; ++j) {
      float v0 = __expf(acc[0][nt][j]);
      float v1 = __expf(acc[1][nt][j]);
      acc[0][nt][j] = v0; acc[1][nt][j] = v1;
      rs0 += v0; rs1 += v1;
    }
  }
  // reduce over lk (lanes lr, lr+16, lr+32, lr+48) -> wave's 256-col row sum
  rs0 += __shfl_xor(rs0, 16); rs0 += __shfl_xor(rs0, 32);
  rs1 += __shfl_xor(rs1, 16); rs1 += __shfl_xor(rs1, 32);
  if (lane < 16) { sRS[w][lane] = rs0; sRS[w][16 + lane] = rs1; }
  __syncthreads();
  float inv0 = 1.0f / (sRS[0][lr] + sRS[1][lr] + sRS[2][lr] + sRS[3][lr]);
  float inv1 = 1.0f / (sRS[0][16 + lr] + sRS[1][16 + lr] + sRS[2][16 + lr] + sRS[3][16 + lr]);

  const int nb = w * 256;
  float* attnz = attn + (size_t)z * 1048576;
  float* csz = cs + (size_t)z * 4096;
#pragma unroll
  for (int nt = 0; nt < 16; ++nt) {
    int n = nb + nt * 16 + lk * 4;
    float4 o0, o1;
    o0.x = acc[0][nt][0] * inv0; o0.y = acc[0][nt][1] * inv0;
    o0.z = acc[0][nt][2] * inv0; o0.w = acc[0][nt][3] * inv0;
    o1.x = acc[1][nt][0] * inv1; o1.y = acc[1][nt][1] * inv1;
    o1.z = acc[1][nt][2] * inv1; o1.w = acc[1][nt][3] * inv1;
    *(float4*)&attnz[(size_t)(q0 + lr) * 1024 + n] = o0;
    *(float4*)&attnz[(size_t)(q0 + 16 + lr) * 1024 + n] = o1;
    // column sums per r = q mod 4: rows lr and 16+lr share r = lr&3; sum the
    // 4 lanes {lr, lr^4, lr^8, lr^12} (same r, same lk) via shfl_xor(4,8)
    float c0 = o0.x + o1.x, c1 = o0.y + o1.y, c2 = o0.z + o1.z, c3 = o0.w + o1.w;
    c0 += __shfl_xor(c0, 4); c0 += __shfl_xor(c0, 8);
    c1 += __shfl_xor(c1, 4); c1 += __shfl_xor(c1, 8);
    c2 += __shfl_xor(c2, 4); c2 += __shfl_xor(c2, 8);
    c3 += __shfl_xor(c3, 4); c3 += __shfl_xor(c3, 8);
    if (lr < 4) {
      float* p = csz + (size_t)lr * 1024 + n;
      atomicAdd(p + 0, c0);
      atomicAdd(p + 1, c1);
      atomicAdd(p + 2, c2);
      atomicAdd(p + 3, c3);
    }
  }
}

// ---------------- abar[b, r*256+d] = (1/1024) sum_{h,k} cs[bh][r][k] * Tv[bh][k][d] ----------------
__global__ __launch_bounds__(256) void abar_kernel(const float* __restrict__ cs,
                                                   const half_t* __restrict__ Tv,
                                                   float* __restrict__ abar) {
  int b = blockIdx.x, r = blockIdx.y, kc = blockIdx.z;
  int d = threadIdx.x;
  __shared__ float scs[4][128];
  for (int idx = d; idx < 512; idx += 256) {
    int h = idx >> 7, k = idx & 127;
    scs[h][k] = cs[(size_t)(b * 4 + h) * 4096 + (size_t)r * 1024 + kc * 128 + k];
  }
  __syncthreads();
  float acc = 0.0f;
  for (int h = 0; h < 4; ++h) {
    const half_t* tv = Tv + (size_t)(b * 4 + h) * 262144 + (size_t)kc * 32768 + d;
#pragma unroll 4
    for (int k = 0; k < 128; ++k)
      acc += scs[h][k] * (float)tv[(size_t)k * 256];
  }
  atomicAdd(&abar[b * 1024 + r * 256 + d], acc * (1.0f / 1024.0f));
}

// ---------------- bcomb[j] = b1[j] + sum_k bo[k] * W1[k][j] ----------------
__global__ __launch_bounds__(256) void bcomb_kernel(const float* __restrict__ bo,
                                                    const float* __restrict__ W1,
                                                    const float* __restrict__ b1,
                                                    float* __restrict__ bcomb) {
  int t = threadIdx.x;
  int j = t & 127, h = t >> 7;
  float acc = 0.0f;
  for (int k = h * 1024; k < h * 1024 + 1024; ++k)
    acc += bo[k] * W1[(size_t)k * 128 + j];
  __shared__ float sm[2][128];
  sm[h][j] = acc;
  __syncthreads();
  if (t < 128) bcomb[t] = sm[0][t] + sm[1][t] + b1[t];
}

// ---------------- out[b][j] = bcomb[j] + sum_c abar[b][c] * Wcomb[c][j] ----------------
__global__ __launch_bounds__(256) void final2_kernel(const float* __restrict__ abar,
                                                     const half_t* __restrict__ Wcomb,
                                                     const float* __restrict__ bcomb,
                                                     float* __restrict__ out) {
  int b = blockIdx.x, t = threadIdx.x;
  int j = t & 127, h = t >> 7;
  __shared__ float sa[1024];
  __shared__ float sm[2][128];
  for (int i = t; i < 1024; i += 256) sa[i] = abar[(size_t)b * 1024 + i];
  __syncthreads();
  float acc = 0.0f;
  for (int c = h * 512; c < h * 512 + 512; ++c)
    acc += sa[c] * (float)Wcomb[(size_t)c * 128 + j];
  sm[h][j] = acc;
  __syncthreads();
  if (t < 128) out[(size_t)b * 128 + t] = sm[0][t] + sm[1][t] + bcomb[t];
}

extern "C" void kernel_launch(void* const* d_in, const int* in_sizes, int n_in,
                              void* d_out, int out_size, void* d_ws, size_t ws_size,
                              hipStream_t stream) {
  const float* query = (const float*)d_in[0];
  const float* key   = (const float*)d_in[1];
  const float* value = (const float*)d_in[2];
  const float* Wq = (const float*)d_in[3];
  const float* bq = (const float*)d_in[4];
  const float* Wk = (const float*)d_in[5];
  const float* bk = (const float*)d_in[6];
  const float* Wv = (const float*)d_in[7];
  const float* bv = (const float*)d_in[8];
  const float* Wo = (const float*)d_in[9];
  const float* bo = (const float*)d_in[10];
  const float* W1 = (const float*)d_in[11];
  const float* b1 = (const float*)d_in[12];

  // workspace layout (bytes)
  char* ws = (char*)d_ws;
  half_t* Tq   = (half_t*)(ws + 0);          // 16M halves  [b][s][1024]  (dead after fused kernel)
  half_t* Tk   = (half_t*)(ws + 33554432);   // 16M halves
  half_t* Tv   = (half_t*)(ws + 67108864);   // 16M halves  (live until abar)
  float*  cs   = (float*)(ws + 100663296);   // [64][4][1024] f32
  float*  abar = (float*)(ws + 101711872);   // [16][1024] f32
  half_t* Wqt  = (half_t*)(ws + 101777408);  // [1024][128] f16
  half_t* Wkt  = (half_t*)(ws + 102039552);  // [1024][256] f16
  half_t* Wvt  = (half_t*)(ws + 102563840);  // [1024][256] f16
  // overlapped onto dead Tq region (only used after the fused attention kernel):
  half_t* W1t   = (half_t*)(ws + 0);         // [128][2048] f16
  half_t* Wcomb = (half_t*)(ws + 524288);    // [1024][128] f16
  float*  bcomb = (float*)(ws + 786432);     // [128] f32

  float* out  = (float*)d_out;
  float* attn = out + 2048;  // [64][1024][1024] f32

  hipMemsetAsync(cs, 0, 1048576 + 65536, stream);  // zero cs + abar

  wtrans_kernel<<<dim3(32, 4), 256, 0, stream>>>(Wq, Wqt, 128, 1024);
  wtrans_kernel<<<dim3(32, 8), 256, 0, stream>>>(Wk, Wkt, 256, 1024);
  wtrans_kernel<<<dim3(32, 8), 256, 0, stream>>>(Wv, Wvt, 256, 1024);

  // projections: T = X @ W + b  (fp32 A staged->fp16, fp16 out)
  gemm_nt<true, true><<<dim3(128, 8, 1), 256, 0, stream>>>(query, nullptr, Wqt, bq, Tq, 128, 1024, 0, 0, 0);
  gemm_nt<true, true><<<dim3(128, 8, 1), 256, 0, stream>>>(key,   nullptr, Wkt, bk, Tk, 256, 1024, 0, 0, 0);
  gemm_nt<true, true><<<dim3(128, 8, 1), 256, 0, stream>>>(value, nullptr, Wvt, bv, Tv, 256, 1024, 0, 0, 0);

  // fused: scores + softmax + fp32 attn write + per-(q%4) column sums
  fused_attn_kernel<<<dim3(32, 64), 256, 0, stream>>>(Tq, Tk, attn, cs);

  // Wcomb = Wo @ W1 (folded tail GEMM), bcomb = bo @ W1 + b1 -- Tq region is dead now
  wtrans_kernel<<<dim3(4, 64), 256, 0, stream>>>(W1, W1t, 2048, 128);
  gemm_nt<true, false><<<dim3(8, 1, 1), 256, 0, stream>>>(Wo, nullptr, W1t, nullptr, Wcomb, 2048, 128, 0, 0, 0);
  bcomb_kernel<<<1, 256, 0, stream>>>(bo, W1, b1, bcomb);

  abar_kernel<<<dim3(16, 4, 8), 256, 0, stream>>>(cs, Tv, abar);
  final2_kernel<<<16, 256, 0, stream>>>(abar, Wcomb, bcomb, out);
}

// Round 7
// 651.610 us; speedup vs baseline: 1.2408x; 1.0938x over previous
//
#include <hip/hip_runtime.h>
#include <hip/hip_bf16.h>

typedef _Float16 half_t;
typedef _Float16 half8 __attribute__((ext_vector_type(8)));
typedef _Float16 half4v __attribute__((ext_vector_type(4)));
typedef float floatx4 __attribute__((ext_vector_type(4)));

// direct global->LDS DMA, 16B per lane; lds ptr must be wave-uniform (HW writes base+lane*16)
__device__ inline void gload16(const half_t* g, half_t* l) {
  __builtin_amdgcn_global_load_lds(
      (const __attribute__((address_space(1))) void*)g,
      (__attribute__((address_space(3))) void*)l, 16, 0, 0);
}

// ---------------- weight transpose + fp32->fp16: Wt[n][k] = W[k][n], W is [K][N] ----------------
__global__ __launch_bounds__(256) void wtrans_kernel(const float* __restrict__ W,
                                                     half_t* __restrict__ Wt, int K, int N) {
  __shared__ float sm[32][33];
  int n0 = blockIdx.x * 32, k0 = blockIdx.y * 32;
  int x = threadIdx.x & 31, y0 = threadIdx.x >> 5;
#pragma unroll
  for (int yy = 0; yy < 4; ++yy) {
    int y = y0 + yy * 8;
    sm[y][x] = W[(size_t)(k0 + y) * N + n0 + x];
  }
  __syncthreads();
#pragma unroll
  for (int yy = 0; yy < 4; ++yy) {
    int y = y0 + yy * 8;
    Wt[(size_t)(n0 + y) * K + k0 + x] = (half_t)sm[x][y];
  }
}

// 3-in-1 wtrans for Wq/Wk/Wv (merged launch: saves 2 dispatch slots).
// grid (32, 20): y<4 -> Wq (K=128), y in [4,12) -> Wk, y in [12,20) -> Wv (K=256). N=1024 all.
__global__ __launch_bounds__(256) void wtrans3_kernel(
    const float* __restrict__ Wq, half_t* __restrict__ Wqt,
    const float* __restrict__ Wk, half_t* __restrict__ Wkt,
    const float* __restrict__ Wv, half_t* __restrict__ Wvt) {
  __shared__ float sm[32][33];
  int y = blockIdx.y;
  const float* W; half_t* Wt; int K, k0;
  if (y < 4)       { W = Wq; Wt = Wqt; K = 128; k0 = y * 32; }
  else if (y < 12) { W = Wk; Wt = Wkt; K = 256; k0 = (y - 4) * 32; }
  else             { W = Wv; Wt = Wvt; K = 256; k0 = (y - 12) * 32; }
  int n0 = blockIdx.x * 32;
  int x = threadIdx.x & 31, y0 = threadIdx.x >> 5;
#pragma unroll
  for (int yy = 0; yy < 4; ++yy) {
    int r = y0 + yy * 8;
    sm[r][x] = W[(size_t)(k0 + r) * 1024 + n0 + x];
  }
  __syncthreads();
#pragma unroll
  for (int yy = 0; yy < 4; ++yy) {
    int r = y0 + yy * 8;
    Wt[(size_t)(n0 + r) * K + k0 + x] = (half_t)sm[x][r];
  }
}

// ---------------- NT GEMM: C[m][n] = sum_k A[m][k]*Bt[n][k] (+bias[n]), fp16 MFMA, fp32 acc ----------------
template <bool AF32, bool BIAS>
__global__ __launch_bounds__(256) void gemm_nt(
    const float* __restrict__ Af, const half_t* __restrict__ Ah,
    const half_t* __restrict__ Bt, const float* __restrict__ bias,
    half_t* __restrict__ C, int K, int ldc,
    size_t aStrideZ, size_t bStrideZ, size_t cStrideZ) {
  __shared__ half_t sA[128 * 32];
  __shared__ half_t sB[128 * 32];
  const int t = threadIdx.x;
  const int m0 = blockIdx.x * 128;
  const int n0 = blockIdx.y * 128;
  const int z = blockIdx.z;
  const half_t* Bz = Bt + bStrideZ * (size_t)z;
  const int w = t >> 6, lane = t & 63;
  const int wm = w & 1, wn = w >> 1;
  const int lr = lane & 15, lk = lane >> 4;
  const int srow = t >> 2, sg = t & 3;

  floatx4 acc[4][4] = {};

  for (int k0 = 0; k0 < K; k0 += 32) {
    __syncthreads();
#pragma unroll
    for (int rep = 0; rep < 2; ++rep) {
      int row = srow + rep * 64;
      int goff = (sg ^ ((row >> 1) & 3)) * 8;
      half8 hv;
      if constexpr (AF32) {
        const float* p = Af + (size_t)(m0 + row) * K + k0 + sg * 8;
        float4 f0 = *(const float4*)p;
        float4 f1 = *(const float4*)(p + 4);
        hv[0] = (half_t)f0.x; hv[1] = (half_t)f0.y;
        hv[2] = (half_t)f0.z; hv[3] = (half_t)f0.w;
        hv[4] = (half_t)f1.x; hv[5] = (half_t)f1.y;
        hv[6] = (half_t)f1.z; hv[7] = (half_t)f1.w;
      } else {
        const half_t* p = Ah + aStrideZ * (size_t)z + (size_t)(m0 + row) * K + k0 + sg * 8;
        hv = *(const half8*)p;
      }
      *(half8*)&sA[row * 32 + goff] = hv;
      const half_t* q = Bz + (size_t)(n0 + row) * K + k0 + sg * 8;
      *(half8*)&sB[row * 32 + goff] = *(const half8*)q;
    }
    __syncthreads();
    half8 af[4], bf[4];
#pragma unroll
    for (int mt = 0; mt < 4; ++mt) {
      int row = wm * 64 + mt * 16 + lr;
      af[mt] = *(const half8*)&sA[row * 32 + ((lk ^ ((row >> 1) & 3)) * 8)];
    }
#pragma unroll
    for (int nt = 0; nt < 4; ++nt) {
      int row = wn * 64 + nt * 16 + lr;
      bf[nt] = *(const half8*)&sB[row * 32 + ((lk ^ ((row >> 1) & 3)) * 8)];
    }
#pragma unroll
    for (int mt = 0; mt < 4; ++mt)
#pragma unroll
      for (int nt = 0; nt < 4; ++nt)
        acc[mt][nt] = __builtin_amdgcn_mfma_f32_16x16x32_f16(bf[nt], af[mt], acc[mt][nt], 0, 0, 0);
  }

  half_t* Cz = C + cStrideZ * (size_t)z;
#pragma unroll
  for (int mt = 0; mt < 4; ++mt) {
    int m = m0 + wm * 64 + mt * 16 + lr;
#pragma unroll
    for (int nt = 0; nt < 4; ++nt) {
      int nb = n0 + wn * 64 + nt * 16 + lk * 4;
      floatx4 a = acc[mt][nt];
      half4v h;
      if constexpr (BIAS) {
        float4 bv = *(const float4*)&bias[nb];
        h[0] = (half_t)(a[0] + bv.x); h[1] = (half_t)(a[1] + bv.y);
        h[2] = (half_t)(a[2] + bv.z); h[3] = (half_t)(a[3] + bv.w);
      } else {
        h[0] = (half_t)a[0]; h[1] = (half_t)a[1];
        h[2] = (half_t)a[2]; h[3] = (half_t)a[3];
      }
      *(half4v*)&Cz[(size_t)m * ldc + nb] = h;
    }
  }
}

// Merged Q/K/V projection: identical body to gemm_nt<true,true>, grid (128,8,3);
// blockIdx.z selects {input, weight^T, bias, output, K}. Saves 2 launches + fills the machine.
__global__ __launch_bounds__(256) void proj_gemm(
    const float* __restrict__ query, const float* __restrict__ key, const float* __restrict__ value,
    const half_t* __restrict__ Wqt, const half_t* __restrict__ Wkt, const half_t* __restrict__ Wvt,
    const float* __restrict__ bq, const float* __restrict__ bk, const float* __restrict__ bv,
    half_t* __restrict__ Tq, half_t* __restrict__ Tk, half_t* __restrict__ Tv) {
  const int z = blockIdx.z;
  const float* Af = z == 0 ? query : (z == 1 ? key : value);
  const half_t* Bt = z == 0 ? Wqt : (z == 1 ? Wkt : Wvt);
  const float* bias = z == 0 ? bq : (z == 1 ? bk : bv);
  half_t* C = z == 0 ? Tq : (z == 1 ? Tk : Tv);
  const int K = z == 0 ? 128 : 256;

  __shared__ half_t sA[128 * 32];
  __shared__ half_t sB[128 * 32];
  const int t = threadIdx.x;
  const int m0 = blockIdx.x * 128;
  const int n0 = blockIdx.y * 128;
  const int w = t >> 6, lane = t & 63;
  const int wm = w & 1, wn = w >> 1;
  const int lr = lane & 15, lk = lane >> 4;
  const int srow = t >> 2, sg = t & 3;

  floatx4 acc[4][4] = {};

  for (int k0 = 0; k0 < K; k0 += 32) {
    __syncthreads();
#pragma unroll
    for (int rep = 0; rep < 2; ++rep) {
      int row = srow + rep * 64;
      int goff = (sg ^ ((row >> 1) & 3)) * 8;
      const float* p = Af + (size_t)(m0 + row) * K + k0 + sg * 8;
      float4 f0 = *(const float4*)p;
      float4 f1 = *(const float4*)(p + 4);
      half8 hv;
      hv[0] = (half_t)f0.x; hv[1] = (half_t)f0.y;
      hv[2] = (half_t)f0.z; hv[3] = (half_t)f0.w;
      hv[4] = (half_t)f1.x; hv[5] = (half_t)f1.y;
      hv[6] = (half_t)f1.z; hv[7] = (half_t)f1.w;
      *(half8*)&sA[row * 32 + goff] = hv;
      const half_t* q = Bt + (size_t)(n0 + row) * K + k0 + sg * 8;
      *(half8*)&sB[row * 32 + goff] = *(const half8*)q;
    }
    __syncthreads();
    half8 af[4], bf[4];
#pragma unroll
    for (int mt = 0; mt < 4; ++mt) {
      int row = wm * 64 + mt * 16 + lr;
      af[mt] = *(const half8*)&sA[row * 32 + ((lk ^ ((row >> 1) & 3)) * 8)];
    }
#pragma unroll
    for (int nt = 0; nt < 4; ++nt) {
      int row = wn * 64 + nt * 16 + lr;
      bf[nt] = *(const half8*)&sB[row * 32 + ((lk ^ ((row >> 1) & 3)) * 8)];
    }
#pragma unroll
    for (int mt = 0; mt < 4; ++mt)
#pragma unroll
      for (int nt = 0; nt < 4; ++nt)
        acc[mt][nt] = __builtin_amdgcn_mfma_f32_16x16x32_f16(bf[nt], af[mt], acc[mt][nt], 0, 0, 0);
  }

#pragma unroll
  for (int mt = 0; mt < 4; ++mt) {
    int m = m0 + wm * 64 + mt * 16 + lr;
#pragma unroll
    for (int nt = 0; nt < 4; ++nt) {
      int nb = n0 + wn * 64 + nt * 16 + lk * 4;
      floatx4 a = acc[mt][nt];
      float4 bvv = *(const float4*)&bias[nb];
      half4v h;
      h[0] = (half_t)(a[0] + bvv.x); h[1] = (half_t)(a[1] + bvv.y);
      h[2] = (half_t)(a[2] + bvv.z); h[3] = (half_t)(a[3] + bvv.w);
      *(half4v*)&C[(size_t)m * 1024 + nb] = h;
    }
  }
}

// ---------------- FUSED scores GEMM + softmax + column sums ----------------
// grid (32 qblocks, 64 z), 256 thr = 4 waves. S = Tq[z][q0:q0+32][:] @ Tk[z]^T in fp32 MFMA acc.
// R5 structure kept: global_load_lds direct staging, triple-buffered sK, counted vmcnt(4) + raw
// s_barrier per stage. R6 counters: FETCH 147 MB vs 66 ideal -> attn write stream was evicting
// Tk/Tq from L2 (all 64 z-slices' working sets ~= whole 32 MB L2). R7 fix: NONTEMPORAL attn
// stores -- output is never re-read; keep it out of L2, keep Tk resident for the 32-block reuse.
__global__ __launch_bounds__(256, 2) void fused_attn_kernel(
    const half_t* __restrict__ Tq, const half_t* __restrict__ Tk,
    float* __restrict__ attn, float* __restrict__ cs) {
  const int z = blockIdx.y;
  const int q0 = blockIdx.x * 32;
  const int t = threadIdx.x;
  const int w = t >> 6, lane = t & 63;
  const int lr = lane & 15, lk = lane >> 4;

  __shared__ half_t sQ[32 * 256];     // linear; XOR-swizzled content (j8 ^= row&7), no pad
  __shared__ half_t sK[3][256 * 32];  // triple-buffered Tk chunks, gemm_nt XOR-swizzle content
  __shared__ float sRS[4][32];

  const half_t* Tqz = Tq + (size_t)z * 262144 + (size_t)q0 * 256;
  const half_t* Tkz = Tk + (size_t)z * 262144;

  // ---- prologue: issue sQ + S(0) + S(1) via global_load_lds ----
#pragma unroll
  for (int r = 0; r < 4; ++r) {
    int i = r * 256 + w * 64 + lane;
    int row = i >> 5, j8 = i & 31;
    gload16(Tqz + (size_t)row * 256 + ((j8 ^ (row & 7)) * 8), &sQ[(r * 256 + w * 64) * 8]);
  }
#pragma unroll
  for (int sp = 0; sp < 2; ++sp) {
#pragma unroll
    for (int r = 0; r < 4; ++r) {
      int i = r * 256 + w * 64 + lane;
      int sl = i >> 2, kg = i & 3;
      int grow = ((sl >> 6) << 8) + (sl & 63);  // g=0 for sp<8
      gload16(Tkz + (size_t)grow * 256 + sp * 32 + ((kg ^ ((sl >> 1) & 3)) * 8),
              &sK[sp][(r * 256 + w * 64) * 8]);
    }
  }

  floatx4 acc[2][16] = {};
#pragma unroll
  for (int s = 0; s < 32; ++s) {
    if (s < 31) {
      asm volatile("s_waitcnt vmcnt(4)" ::: "memory");
    } else {
      asm volatile("s_waitcnt vmcnt(0)" ::: "memory");
    }
    __builtin_amdgcn_sched_barrier(0);
    __builtin_amdgcn_s_barrier();

    if (s + 2 < 32) {
      const int sp = s + 2, g2 = sp >> 3, ks2 = sp & 7;
      half_t* base = &sK[sp % 3][0];
#pragma unroll
      for (int r = 0; r < 4; ++r) {
        int i = r * 256 + w * 64 + lane;
        int sl = i >> 2, kg = i & 3;
        int grow = ((sl >> 6) << 8) + g2 * 64 + (sl & 63);
        gload16(Tkz + (size_t)grow * 256 + ks2 * 32 + ((kg ^ ((sl >> 1) & 3)) * 8),
                base + (r * 256 + w * 64) * 8);
      }
    }

    const int g = s >> 3, ks = s & 7;
    const half_t* kb = &sK[s % 3][0];
    const int j8 = ((ks * 4 + lk) ^ (lr & 7)) * 8;
    half8 af0 = *(const half8*)&sQ[lr * 256 + j8];
    half8 af1 = *(const half8*)&sQ[(16 + lr) * 256 + j8];
#pragma unroll
    for (int l = 0; l < 4; ++l) {
      int sl = w * 64 + l * 16 + lr;
      half8 bf = *(const half8*)&kb[sl * 32 + ((lk ^ ((sl >> 1) & 3)) * 8)];
      acc[0][g * 4 + l] = __builtin_amdgcn_mfma_f32_16x16x32_f16(bf, af0, acc[0][g * 4 + l], 0, 0, 0);
      acc[1][g * 4 + l] = __builtin_amdgcn_mfma_f32_16x16x32_f16(bf, af1, acc[1][g * 4 + l], 0, 0, 0);
    }
  }

  // exp (reference softmax has NO max-subtraction) + per-lane partial row sums
  float rs0 = 0.0f, rs1 = 0.0f;
#pragma unroll
  for (int nt = 0; nt < 16; ++nt) {
#pragma unroll
    for (int j = 0; j < 4; ++j) {
      float v0 = __expf(acc[0][nt][j]);
      float v1 = __expf(acc[1][nt][j]);
      acc[0][nt][j] = v0; acc[1][nt][j] = v1;
      rs0 += v0; rs1 += v1;
    }
  }
  rs0 += __shfl_xor(rs0, 16); rs0 += __shfl_xor(rs0, 32);
  rs1 += __shfl_xor(rs1, 16); rs1 += __shfl_xor(rs1, 32);
  if (lane < 16) { sRS[w][lane] = rs0; sRS[w][16 + lane] = rs1; }
  __syncthreads();
  float inv0 = 1.0f / (sRS[0][lr] + sRS[1][lr] + sRS[2][lr] + sRS[3][lr]);
  float inv1 = 1.0f / (sRS[0][16 + lr] + sRS[1][16 + lr] + sRS[2][16 + lr] + sRS[3][16 + lr]);

  const int nb = w * 256;
  float* attnz = attn + (size_t)z * 1048576;
  float* csz = cs + (size_t)z * 4096;
#pragma unroll
  for (int nt = 0; nt < 16; ++nt) {
    int n = nb + nt * 16 + lk * 4;
    floatx4 o0, o1;
    o0[0] = acc[0][nt][0] * inv0; o0[1] = acc[0][nt][1] * inv0;
    o0[2] = acc[0][nt][2] * inv0; o0[3] = acc[0][nt][3] * inv0;
    o1[0] = acc[1][nt][0] * inv1; o1[1] = acc[1][nt][1] * inv1;
    o1[2] = acc[1][nt][2] * inv1; o1[3] = acc[1][nt][3] * inv1;
    // nontemporal: attn is write-once, never re-read -> bypass L2, keep Tk/Tq resident
    __builtin_nontemporal_store(o0, (floatx4*)&attnz[(size_t)(q0 + lr) * 1024 + n]);
    __builtin_nontemporal_store(o1, (floatx4*)&attnz[(size_t)(q0 + 16 + lr) * 1024 + n]);
    float c0 = o0[0] + o1[0], c1 = o0[1] + o1[1], c2 = o0[2] + o1[2], c3 = o0[3] + o1[3];
    c0 += __shfl_xor(c0, 4); c0 += __shfl_xor(c0, 8);
    c1 += __shfl_xor(c1, 4); c1 += __shfl_xor(c1, 8);
    c2 += __shfl_xor(c2, 4); c2 += __shfl_xor(c2, 8);
    c3 += __shfl_xor(c3, 4); c3 += __shfl_xor(c3, 8);
    if (lr < 4) {
      float* p = csz + (size_t)lr * 1024 + n;
      atomicAdd(p + 0, c0);
      atomicAdd(p + 1, c1);
      atomicAdd(p + 2, c2);
      atomicAdd(p + 3, c3);
    }
  }
}

// ---------------- abar[b, r*256+d] = (1/1024) sum_{h,k} cs[bh][r][k] * Tv[bh][k][d] ----------------
__global__ __launch_bounds__(256) void abar_kernel(const float* __restrict__ cs,
                                                   const half_t* __restrict__ Tv,
                                                   float* __restrict__ abar) {
  int b = blockIdx.x, r = blockIdx.y, kc = blockIdx.z;
  int d = threadIdx.x;
  __shared__ float scs[4][128];
  for (int idx = d; idx < 512; idx += 256) {
    int h = idx >> 7, k = idx & 127;
    scs[h][k] = cs[(size_t)(b * 4 + h) * 4096 + (size_t)r * 1024 + kc * 128 + k];
  }
  __syncthreads();
  float acc = 0.0f;
  for (int h = 0; h < 4; ++h) {
    const half_t* tv = Tv + (size_t)(b * 4 + h) * 262144 + (size_t)kc * 32768 + d;
#pragma unroll 4
    for (int k = 0; k < 128; ++k)
      acc += scs[h][k] * (float)tv[(size_t)k * 256];
  }
  atomicAdd(&abar[b * 1024 + r * 256 + d], acc * (1.0f / 1024.0f));
}

// ---------------- bcomb[j] = b1[j] + sum_k bo[k] * W1[k][j] ----------------
__global__ __launch_bounds__(256) void bcomb_kernel(const float* __restrict__ bo,
                                                    const float* __restrict__ W1,
                                                    const float* __restrict__ b1,
                                                    float* __restrict__ bcomb) {
  int t = threadIdx.x;
  int j = t & 127, h = t >> 7;
  float acc = 0.0f;
  for (int k = h * 1024; k < h * 1024 + 1024; ++k)
    acc += bo[k] * W1[(size_t)k * 128 + j];
  __shared__ float sm[2][128];
  sm[h][j] = acc;
  __syncthreads();
  if (t < 128) bcomb[t] = sm[0][t] + sm[1][t] + b1[t];
}

// ---------------- out[b][j] = bcomb[j] + sum_c abar[b][c] * Wcomb[c][j] ----------------
__global__ __launch_bounds__(256) void final2_kernel(const float* __restrict__ abar,
                                                     const half_t* __restrict__ Wcomb,
                                                     const float* __restrict__ bcomb,
                                                     float* __restrict__ out) {
  int b = blockIdx.x, t = threadIdx.x;
  int j = t & 127, h = t >> 7;
  __shared__ float sa[1024];
  __shared__ float sm[2][128];
  for (int i = t; i < 1024; i += 256) sa[i] = abar[(size_t)b * 1024 + i];
  __syncthreads();
  float acc = 0.0f;
  for (int c = h * 512; c < h * 512 + 512; ++c)
    acc += sa[c] * (float)Wcomb[(size_t)c * 128 + j];
  sm[h][j] = acc;
  __syncthreads();
  if (t < 128) out[(size_t)b * 128 + t] = sm[0][t] + sm[1][t] + bcomb[t];
}

extern "C" void kernel_launch(void* const* d_in, const int* in_sizes, int n_in,
                              void* d_out, int out_size, void* d_ws, size_t ws_size,
                              hipStream_t stream) {
  const float* query = (const float*)d_in[0];
  const float* key   = (const float*)d_in[1];
  const float* value = (const float*)d_in[2];
  const float* Wq = (const float*)d_in[3];
  const float* bq = (const float*)d_in[4];
  const float* Wk = (const float*)d_in[5];
  const float* bk = (const float*)d_in[6];
  const float* Wv = (const float*)d_in[7];
  const float* bv = (const float*)d_in[8];
  const float* Wo = (const float*)d_in[9];
  const float* bo = (const float*)d_in[10];
  const float* W1 = (const float*)d_in[11];
  const float* b1 = (const float*)d_in[12];

  // workspace layout (bytes)
  char* ws = (char*)d_ws;
  half_t* Tq   = (half_t*)(ws + 0);          // 16M halves  [b][s][1024]  (dead after fused kernel)
  half_t* Tk   = (half_t*)(ws + 33554432);   // 16M halves
  half_t* Tv   = (half_t*)(ws + 67108864);   // 16M halves  (live until abar)
  float*  cs   = (float*)(ws + 100663296);   // [64][4][1024] f32
  float*  abar = (float*)(ws + 101711872);   // [16][1024] f32
  half_t* Wqt  = (half_t*)(ws + 101777408);  // [1024][128] f16
  half_t* Wkt  = (half_t*)(ws + 102039552);  // [1024][256] f16
  half_t* Wvt  = (half_t*)(ws + 102563840);  // [1024][256] f16
  // overlapped onto dead Tq region (only used after the fused attention kernel):
  half_t* W1t   = (half_t*)(ws + 0);         // [128][2048] f16
  half_t* Wcomb = (half_t*)(ws + 524288);    // [1024][128] f16
  float*  bcomb = (float*)(ws + 786432);     // [128] f32

  float* out  = (float*)d_out;
  float* attn = out + 2048;  // [64][1024][1024] f32

  hipMemsetAsync(cs, 0, 1048576 + 65536, stream);  // zero cs + abar

  // merged 3-in-1 weight transpose (was 3 launches)
  wtrans3_kernel<<<dim3(32, 20), 256, 0, stream>>>(Wq, Wqt, Wk, Wkt, Wv, Wvt);

  // merged Q/K/V projections (was 3 launches): grid.z selects input/weight/bias/output/K
  proj_gemm<<<dim3(128, 8, 3), 256, 0, stream>>>(query, key, value, Wqt, Wkt, Wvt,
                                                 bq, bk, bv, Tq, Tk, Tv);

  // fused: scores + softmax + nontemporal fp32 attn write + per-(q%4) column sums
  fused_attn_kernel<<<dim3(32, 64), 256, 0, stream>>>(Tq, Tk, attn, cs);

  // Wcomb = Wo @ W1 (folded tail GEMM), bcomb = bo @ W1 + b1 -- Tq region is dead now
  wtrans_kernel<<<dim3(4, 64), 256, 0, stream>>>(W1, W1t, 2048, 128);
  gemm_nt<true, false><<<dim3(8, 1, 1), 256, 0, stream>>>(Wo, nullptr, W1t, nullptr, Wcomb, 2048, 128, 0, 0, 0);
  bcomb_kernel<<<1, 256, 0, stream>>>(bo, W1, b1, bcomb);

  abar_kernel<<<dim3(16, 4, 8), 256, 0, stream>>>(cs, Tv, abar);
  final2_kernel<<<16, 256, 0, stream>>>(abar, Wcomb, bcomb, out);
}